// Round 5
// baseline (875.598 us; speedup 1.0000x reference)
//
#include <hip/hip_runtime.h>
#include <hip/hip_bf16.h>

#define H 16
#define NW 20
#define SCAN_TILE 2048  // 256 threads * 8 elems

__device__ __forceinline__ float bf2f(unsigned short u) {
    union { unsigned int u; float f; } c; c.u = ((unsigned int)u) << 16; return c.f;
}

// round-to-nearest-even f32 -> bf16 bits
__device__ __forceinline__ unsigned short f2bf(float f) {
    union { float f; unsigned int u; } c; c.f = f;
    unsigned int u = c.u;
    unsigned int r = (u + 0x7fffu + ((u >> 16) & 1u)) >> 16;
    return (unsigned short)r;
}

__device__ __forceinline__ unsigned int packbf2(float a, float b) {
    return (unsigned int)f2bf(a) | ((unsigned int)f2bf(b) << 16);
}

// unpack 8 bf16 (uint4) -> 8 floats, element order preserved
__device__ __forceinline__ void unpack8(uint4 u, float* f) {
    union { unsigned int u; float f; } c;
    c.u = u.x << 16; f[0] = c.f; c.u = u.x & 0xffff0000u; f[1] = c.f;
    c.u = u.y << 16; f[2] = c.f; c.u = u.y & 0xffff0000u; f[3] = c.f;
    c.u = u.z << 16; f[4] = c.f; c.u = u.z & 0xffff0000u; f[5] = c.f;
    c.u = u.w << 16; f[6] = c.f; c.u = u.w & 0xffff0000u; f[7] = c.f;
}

// ---------------- weight conversion: bf16 -> f32 staging ----------------
struct WPtrs { const unsigned short* src[NW]; int len[NW]; int off[NW]; };

__global__ void cvt_weights_kernel(WPtrs p, float* __restrict__ dst) {
    int a = blockIdx.x;
    const unsigned short* s = p.src[a];
    float* d = dst + p.off[a];
    int n = p.len[a];
    for (int t = threadIdx.x; t < n; t += blockDim.x) d[t] = bf2f(s[t]);
}

// ---------------- node encoder: scalar -> h -> h MLP (f32 out) ----------------
__global__ __launch_bounds__(256) void encode_kernel(
    const unsigned short* __restrict__ xin, int n,
    const float* __restrict__ W1, const float* __restrict__ b1,
    const float* __restrict__ W2, const float* __restrict__ b2,
    float* __restrict__ out)
{
    int i = blockIdx.x * blockDim.x + threadIdx.x;
    if (i >= n) return;
    float v = bf2f(xin[i]);
    float h[H];
    #pragma unroll
    for (int o = 0; o < H; ++o) {
        float t = W1[o] * v + b1[o];
        h[o] = t > 0.f ? t : 0.f;
    }
    float acc[H];
    #pragma unroll
    for (int o = 0; o < H; ++o) acc[o] = b2[o];
    #pragma unroll
    for (int k = 0; k < H; ++k) {
        float hk = h[k];
        #pragma unroll
        for (int o = 0; o < H; ++o) acc[o] += W2[o * H + k] * hk;
    }
    float4* dst = (float4*)(out + (size_t)i * H);
    dst[0] = make_float4(acc[0], acc[1], acc[2], acc[3]);
    dst[1] = make_float4(acc[4], acc[5], acc[6], acc[7]);
    dst[2] = make_float4(acc[8], acc[9], acc[10], acc[11]);
    dst[3] = make_float4(acc[12], acc[13], acc[14], acc[15]);
}

// ---------------- CSR build: histogram -> 3-pass scan -> fill ----------------
__global__ __launch_bounds__(256) void hist_kernel(
    const int* __restrict__ recv, int n_edges, int* __restrict__ cnt)
{
    int e = blockIdx.x * blockDim.x + threadIdx.x;
    if (e < n_edges) atomicAdd(&cnt[recv[e]], 1);
}

__global__ __launch_bounds__(256) void scan_part_kernel(
    const int* __restrict__ cnt, int n, int* __restrict__ blocksum)
{
    int base = blockIdx.x * SCAN_TILE + threadIdx.x * 8;
    int s = 0;
    #pragma unroll
    for (int k = 0; k < 8; ++k) { int i = base + k; if (i < n) s += cnt[i]; }
    __shared__ int red[256];
    red[threadIdx.x] = s;
    __syncthreads();
    for (int off = 128; off > 0; off >>= 1) {
        if (threadIdx.x < off) red[threadIdx.x] += red[threadIdx.x + off];
        __syncthreads();
    }
    if (threadIdx.x == 0) blocksum[blockIdx.x] = red[0];
}

__global__ __launch_bounds__(1024) void scan_blocksums_kernel(
    int* __restrict__ blocksum, int nb, int n, int* __restrict__ row_start)
{
    __shared__ int sums[1024];
    int t = threadIdx.x;
    int v = (t < nb) ? blocksum[t] : 0;
    sums[t] = v;
    __syncthreads();
    for (int off = 1; off < 1024; off <<= 1) {
        int u = (t >= off) ? sums[t - off] : 0;
        __syncthreads();
        sums[t] += u;
        __syncthreads();
    }
    if (t < nb) blocksum[t] = sums[t] - v;
    if (t == 1023) row_start[n] = sums[1023];
}

__global__ __launch_bounds__(256) void scan_final_kernel(
    const int* __restrict__ cnt, int n, const int* __restrict__ blocksum,
    int* __restrict__ row_start, int* __restrict__ cursor)
{
    int t = threadIdx.x;
    int base = blockIdx.x * SCAN_TILE + t * 8;
    int loc[8]; int s = 0;
    #pragma unroll
    for (int k = 0; k < 8; ++k) { int i = base + k; loc[k] = (i < n) ? cnt[i] : 0; s += loc[k]; }
    __shared__ int sums[256];
    sums[t] = s;
    __syncthreads();
    for (int off = 1; off < 256; off <<= 1) {
        int u = (t >= off) ? sums[t - off] : 0;
        __syncthreads();
        sums[t] += u;
        __syncthreads();
    }
    int run = blocksum[blockIdx.x] + sums[t] - s;
    #pragma unroll
    for (int k = 0; k < 8; ++k) {
        int i = base + k;
        if (i < n) { row_start[i] = run; cursor[i] = run; run += loc[k]; }
    }
}

__global__ __launch_bounds__(256) void fill_kernel(
    const int* __restrict__ recv, int n_edges,
    int* __restrict__ cursor, int* __restrict__ elist)
{
    int e = blockIdx.x * blockDim.x + threadIdx.x;
    if (e >= n_edges) return;
    int pos = atomicAdd(&cursor[recv[e]], 1);
    elist[pos] = e;
}

// ------- edge update: MLP(concat[nf_s, nf_r, ef]) -> bf16 ef; optional fused encoder -------
__global__ __launch_bounds__(256) void edge_update_kernel(
    const float* __restrict__ nf, unsigned short* __restrict__ ef,
    const unsigned short* __restrict__ raw_edges, int use_enc,
    const int* __restrict__ senders, const int* __restrict__ recv, int n_edges,
    const float* __restrict__ W1, const float* __restrict__ b1,
    const float* __restrict__ W2, const float* __restrict__ b2,
    const float* __restrict__ eW1, const float* __restrict__ eb1,
    const float* __restrict__ eW2, const float* __restrict__ eb2)
{
    int e = blockIdx.x * blockDim.x + threadIdx.x;
    if (e >= n_edges) return;
    int s = senders[e], r = recv[e];

    float h[H];
    #pragma unroll
    for (int o = 0; o < H; ++o) h[o] = b1[o];

    // sender features: FMA streamed, no x buffer
    const float4* ps = (const float4*)(nf + (size_t)s * H);
    #pragma unroll
    for (int q = 0; q < 4; ++q) {
        float4 v = ps[q];
        int k = q * 4;
        #pragma unroll
        for (int o = 0; o < H; ++o)
            h[o] += W1[o*48 + k] * v.x + W1[o*48 + k+1] * v.y
                  + W1[o*48 + k+2] * v.z + W1[o*48 + k+3] * v.w;
    }
    // receiver features
    const float4* pr = (const float4*)(nf + (size_t)r * H);
    #pragma unroll
    for (int q = 0; q < 4; ++q) {
        float4 v = pr[q];
        int k = 16 + q * 4;
        #pragma unroll
        for (int o = 0; o < H; ++o)
            h[o] += W1[o*48 + k] * v.x + W1[o*48 + k+1] * v.y
                  + W1[o*48 + k+2] * v.z + W1[o*48 + k+3] * v.w;
    }
    // edge features: either fused encoder output or bf16 ef row
    float xe[H];
    if (use_enc) {
        float v = bf2f(raw_edges[e]);
        float t[H];
        #pragma unroll
        for (int o = 0; o < H; ++o) {
            float tt = eW1[o] * v + eb1[o];
            t[o] = tt > 0.f ? tt : 0.f;
        }
        #pragma unroll
        for (int o = 0; o < H; ++o) {
            float a = eb2[o];
            #pragma unroll
            for (int k = 0; k < H; ++k) a += eW2[o * H + k] * t[k];
            xe[o] = a;
        }
    } else {
        const uint4* pe = (const uint4*)(ef + (size_t)e * H);
        uint4 u0 = pe[0], u1 = pe[1];
        unpack8(u0, xe);
        unpack8(u1, xe + 8);
    }
    #pragma unroll
    for (int k = 0; k < H; ++k) {
        float xk = xe[k];
        #pragma unroll
        for (int o = 0; o < H; ++o) h[o] += W1[o*48 + 32 + k] * xk;
    }
    #pragma unroll
    for (int o = 0; o < H; ++o) h[o] = h[o] > 0.f ? h[o] : 0.f;

    float acc[H];
    #pragma unroll
    for (int o = 0; o < H; ++o) acc[o] = b2[o];
    #pragma unroll
    for (int k = 0; k < H; ++k) {
        float hk = h[k];
        #pragma unroll
        for (int o = 0; o < H; ++o) acc[o] += W2[o * H + k] * hk;
    }
    uint4 o0, o1;
    o0.x = packbf2(acc[0], acc[1]);  o0.y = packbf2(acc[2], acc[3]);
    o0.z = packbf2(acc[4], acc[5]);  o0.w = packbf2(acc[6], acc[7]);
    o1.x = packbf2(acc[8], acc[9]);  o1.y = packbf2(acc[10], acc[11]);
    o1.z = packbf2(acc[12], acc[13]); o1.w = packbf2(acc[14], acc[15]);
    uint4* dst = (uint4*)(ef + (size_t)e * H);
    dst[0] = o0; dst[1] = o1;
}

// ---------------- node update: gather incoming bf16 ef via CSR, then MLP ----------------
__global__ __launch_bounds__(256) void node_update_kernel(
    float* __restrict__ nf, const unsigned short* __restrict__ ef,
    const int* __restrict__ row_start, const int* __restrict__ elist, int n_nodes,
    const float* __restrict__ W1, const float* __restrict__ b1,
    const float* __restrict__ W2, const float* __restrict__ b2)
{
    int i = blockIdx.x * blockDim.x + threadIdx.x;
    if (i >= n_nodes) return;
    int lo = row_start[i], hi = row_start[i + 1];
    float a[H];
    #pragma unroll
    for (int o = 0; o < H; ++o) a[o] = 0.f;
    for (int j = lo; j < hi; ++j) {
        int e = elist[j];
        const uint4* pe = (const uint4*)(ef + (size_t)e * H);
        uint4 u0 = pe[0], u1 = pe[1];
        float f[H];
        unpack8(u0, f);
        unpack8(u1, f + 8);
        #pragma unroll
        for (int o = 0; o < H; ++o) a[o] += f[o];
    }
    int d = hi - lo;
    float rd = 1.0f / (float)(d > 1 ? d : 1);

    float h[H];
    #pragma unroll
    for (int o = 0; o < H; ++o) h[o] = b1[o];
    const float4* pn = (const float4*)(nf + (size_t)i * H);
    #pragma unroll
    for (int q = 0; q < 4; ++q) {
        float4 v = pn[q];
        int k = q * 4;
        #pragma unroll
        for (int o = 0; o < H; ++o)
            h[o] += W1[o*32 + k] * v.x + W1[o*32 + k+1] * v.y
                  + W1[o*32 + k+2] * v.z + W1[o*32 + k+3] * v.w;
    }
    #pragma unroll
    for (int k = 0; k < H; ++k) {
        float xk = a[k] * rd;
        #pragma unroll
        for (int o = 0; o < H; ++o) h[o] += W1[o*32 + 16 + k] * xk;
    }
    #pragma unroll
    for (int o = 0; o < H; ++o) h[o] = h[o] > 0.f ? h[o] : 0.f;
    float acc[H];
    #pragma unroll
    for (int o = 0; o < H; ++o) acc[o] = b2[o];
    #pragma unroll
    for (int k = 0; k < H; ++k) {
        float hk = h[k];
        #pragma unroll
        for (int o = 0; o < H; ++o) acc[o] += W2[o * H + k] * hk;
    }
    float4* dst = (float4*)(nf + (size_t)i * H);
    dst[0] = make_float4(acc[0], acc[1], acc[2], acc[3]);
    dst[1] = make_float4(acc[4], acc[5], acc[6], acc[7]);
    dst[2] = make_float4(acc[8], acc[9], acc[10], acc[11]);
    dst[3] = make_float4(acc[12], acc[13], acc[14], acc[15]);
}

// ---------------- bidirectional edge averaging (in place, bf16) ----------------
__global__ __launch_bounds__(256) void bi_avg_kernel(
    unsigned short* __restrict__ ef, const int* __restrict__ bi, int n_bi)
{
    int p = blockIdx.x * blockDim.x + threadIdx.x;
    if (p >= n_bi) return;
    int i = bi[p], j = bi[n_bi + p];
    uint4* pi = (uint4*)(ef + (size_t)i * H);
    uint4* pj = (uint4*)(ef + (size_t)j * H);
    uint4 a0 = pi[0], a1 = pi[1], b0 = pj[0], b1 = pj[1];
    float fa[H], fb[H];
    unpack8(a0, fa); unpack8(a1, fa + 8);
    unpack8(b0, fb); unpack8(b1, fb + 8);
    float m[H];
    #pragma unroll
    for (int o = 0; o < H; ++o) m[o] = 0.5f * (fa[o] + fb[o]);
    uint4 o0, o1;
    o0.x = packbf2(m[0], m[1]);  o0.y = packbf2(m[2], m[3]);
    o0.z = packbf2(m[4], m[5]);  o0.w = packbf2(m[6], m[7]);
    o1.x = packbf2(m[8], m[9]);  o1.y = packbf2(m[10], m[11]);
    o1.z = packbf2(m[12], m[13]); o1.w = packbf2(m[14], m[15]);
    pi[0] = o0; pi[1] = o1;
    pj[0] = o0; pj[1] = o1;
}

// ---------------- decoder: h -> h -> 1, tril mask, emit f32 outputs ----------------
__global__ __launch_bounds__(256) void decode_kernel(
    const unsigned short* __restrict__ ef, const int* __restrict__ recv,
    const int* __restrict__ send, int n_edges,
    const float* __restrict__ W1, const float* __restrict__ b1,
    const float* __restrict__ W2, const float* __restrict__ b2,
    float* __restrict__ out)
{
    int e = blockIdx.x * blockDim.x + threadIdx.x;
    if (e >= n_edges) return;
    const uint4* pe = (const uint4*)(ef + (size_t)e * H);
    uint4 u0 = pe[0], u1 = pe[1];
    float x[H];
    unpack8(u0, x);
    unpack8(u1, x + 8);
    float h[H];
    #pragma unroll
    for (int o = 0; o < H; ++o) h[o] = b1[o];
    #pragma unroll
    for (int k = 0; k < H; ++k) {
        float xk = x[k];
        #pragma unroll
        for (int o = 0; o < H; ++o) h[o] += W1[o * H + k] * xk;
    }
    float val = b2[0];
    #pragma unroll
    for (int k = 0; k < H; ++k) {
        float hk = h[k] > 0.f ? h[k] : 0.f;
        val += W2[k] * hk;
    }
    int r = recv[e], s = send[e];
    val = (r >= s) ? val : 0.0f;
    out[e] = val;
    out[(size_t)n_edges + e] = bf2f(f2bf((float)r));
    out[2 * (size_t)n_edges + e] = bf2f(f2bf((float)s));
}

// ---------------- host launcher ----------------
extern "C" void kernel_launch(void* const* d_in, const int* in_sizes, int n_in,
                              void* d_out, int out_size, void* d_ws, size_t ws_size,
                              hipStream_t stream) {
    const unsigned short* nodes = (const unsigned short*)d_in[0];
    const unsigned short* edges = (const unsigned short*)d_in[1];
    const int* receivers = (const int*)d_in[2];
    const int* senders   = (const int*)d_in[3];
    const int* bi        = (const int*)d_in[4];
    const int n_nodes = in_sizes[0];
    const int n_edges = in_sizes[1];
    const int n_bi    = in_sizes[4] / 2;

    static const int wl[NW] = {16,16,256,16, 16,16,256,16,
                               3840,80,1280,80, 2560,80,1280,80,
                               256,16,16,1};
    WPtrs wp;
    {
        int off = 0;
        for (int a = 0; a < NW; ++a) {
            wp.src[a] = (const unsigned short*)d_in[5 + a];
            wp.len[a] = wl[a];
            wp.off[a] = off;
            off += wl[a];
        }
    }
    float* wf = (float*)d_ws;
    const float* Wf[NW];
    for (int a = 0; a < NW; ++a) Wf[a] = wf + wp.off[a];

    float* nf = wf + 10240;                                  // [n_nodes][16] f32
    unsigned short* ef = (unsigned short*)(nf + (size_t)n_nodes * H);  // [n_edges][16] bf16
    int* cnt       = (int*)(ef + (size_t)n_edges * H);       // [n_nodes]
    int* row_start = cnt + n_nodes;                          // [n_nodes+1]
    int* cursor    = row_start + n_nodes + 1;                // [n_nodes]
    int* elist     = cursor + n_nodes;                       // [n_edges]
    int* blocksum  = elist + n_edges;                        // [<=1024]

    const int bn = 256;
    const int nb_scan = (n_nodes + SCAN_TILE - 1) / SCAN_TILE;

    cvt_weights_kernel<<<NW, 256, 0, stream>>>(wp, wf);
    encode_kernel<<<(n_nodes + bn - 1) / bn, bn, 0, stream>>>(
        nodes, n_nodes, Wf[0], Wf[1], Wf[2], Wf[3], nf);

    // CSR build (once per launch; receivers are fixed input)
    hipMemsetAsync(cnt, 0, (size_t)n_nodes * 4, stream);
    hist_kernel<<<(n_edges + bn - 1) / bn, bn, 0, stream>>>(receivers, n_edges, cnt);
    scan_part_kernel<<<nb_scan, 256, 0, stream>>>(cnt, n_nodes, blocksum);
    scan_blocksums_kernel<<<1, 1024, 0, stream>>>(blocksum, nb_scan, n_nodes, row_start);
    scan_final_kernel<<<nb_scan, 256, 0, stream>>>(cnt, n_nodes, blocksum, row_start, cursor);
    fill_kernel<<<(n_edges + bn - 1) / bn, bn, 0, stream>>>(receivers, n_edges, cursor, elist);

    for (int r = 0; r < 5; ++r) {
        edge_update_kernel<<<(n_edges + bn - 1) / bn, bn, 0, stream>>>(
            nf, ef, edges, (r == 0) ? 1 : 0,
            senders, receivers, n_edges,
            Wf[8] + r * 3 * H * H, Wf[9] + r * H,
            Wf[10] + r * H * H,    Wf[11] + r * H,
            Wf[4], Wf[5], Wf[6], Wf[7]);
        node_update_kernel<<<(n_nodes + bn - 1) / bn, bn, 0, stream>>>(
            nf, ef, row_start, elist, n_nodes,
            Wf[12] + r * 2 * H * H, Wf[13] + r * H,
            Wf[14] + r * H * H,     Wf[15] + r * H);
    }

    bi_avg_kernel<<<(n_bi + bn - 1) / bn, bn, 0, stream>>>(ef, bi, n_bi);
    decode_kernel<<<(n_edges + bn - 1) / bn, bn, 0, stream>>>(
        ef, receivers, senders, n_edges,
        Wf[16], Wf[17], Wf[18], Wf[19], (float*)d_out);
}

// Round 6
// 812.518 us; speedup vs baseline: 1.0776x; 1.0776x over previous
//
#include <hip/hip_runtime.h>
#include <hip/hip_bf16.h>

#define H 16
#define NW 20
#define SCAN_TILE 2048  // 256 threads * 8 elems

__device__ __forceinline__ float bf2f(unsigned short u) {
    union { unsigned int u; float f; } c; c.u = ((unsigned int)u) << 16; return c.f;
}

// round-to-nearest-even f32 -> bf16 bits
__device__ __forceinline__ unsigned short f2bf(float f) {
    union { float f; unsigned int u; } c; c.f = f;
    unsigned int u = c.u;
    unsigned int r = (u + 0x7fffu + ((u >> 16) & 1u)) >> 16;
    return (unsigned short)r;
}

__device__ __forceinline__ unsigned int packbf2(float a, float b) {
    return (unsigned int)f2bf(a) | ((unsigned int)f2bf(b) << 16);
}

// unpack 8 bf16 (uint4) -> 8 floats, element order preserved
__device__ __forceinline__ void unpack8(uint4 u, float* f) {
    union { unsigned int u; float f; } c;
    c.u = u.x << 16; f[0] = c.f; c.u = u.x & 0xffff0000u; f[1] = c.f;
    c.u = u.y << 16; f[2] = c.f; c.u = u.y & 0xffff0000u; f[3] = c.f;
    c.u = u.z << 16; f[4] = c.f; c.u = u.z & 0xffff0000u; f[5] = c.f;
    c.u = u.w << 16; f[6] = c.f; c.u = u.w & 0xffff0000u; f[7] = c.f;
}

// ---------------- weight conversion: bf16 -> f32 staging ----------------
struct WPtrs { const unsigned short* src[NW]; int len[NW]; int off[NW]; };

__global__ void cvt_weights_kernel(WPtrs p, float* __restrict__ dst) {
    int a = blockIdx.x;
    const unsigned short* s = p.src[a];
    float* d = dst + p.off[a];
    int n = p.len[a];
    for (int t = threadIdx.x; t < n; t += blockDim.x) d[t] = bf2f(s[t]);
}

// ---------------- node encoder: scalar -> h -> h MLP (f32 out) ----------------
__global__ __launch_bounds__(256) void encode_kernel(
    const unsigned short* __restrict__ xin, int n,
    const float* __restrict__ W1, const float* __restrict__ b1,
    const float* __restrict__ W2, const float* __restrict__ b2,
    float* __restrict__ out)
{
    int i = blockIdx.x * blockDim.x + threadIdx.x;
    if (i >= n) return;
    float v = bf2f(xin[i]);
    float h[H];
    #pragma unroll
    for (int o = 0; o < H; ++o) {
        float t = W1[o] * v + b1[o];
        h[o] = t > 0.f ? t : 0.f;
    }
    float acc[H];
    #pragma unroll
    for (int o = 0; o < H; ++o) acc[o] = b2[o];
    #pragma unroll
    for (int k = 0; k < H; ++k) {
        float hk = h[k];
        #pragma unroll
        for (int o = 0; o < H; ++o) acc[o] += W2[o * H + k] * hk;
    }
    float4* dst = (float4*)(out + (size_t)i * H);
    dst[0] = make_float4(acc[0], acc[1], acc[2], acc[3]);
    dst[1] = make_float4(acc[4], acc[5], acc[6], acc[7]);
    dst[2] = make_float4(acc[8], acc[9], acc[10], acc[11]);
    dst[3] = make_float4(acc[12], acc[13], acc[14], acc[15]);
}

// ---------------- CSR build: histogram -> 3-pass scan -> fill ----------------
__global__ __launch_bounds__(256) void hist_kernel(
    const int* __restrict__ recv, int n_edges, int* __restrict__ cnt)
{
    int e = blockIdx.x * blockDim.x + threadIdx.x;
    if (e < n_edges) atomicAdd(&cnt[recv[e]], 1);
}

__global__ __launch_bounds__(256) void scan_part_kernel(
    const int* __restrict__ cnt, int n, int* __restrict__ blocksum)
{
    int base = blockIdx.x * SCAN_TILE + threadIdx.x * 8;
    int s = 0;
    #pragma unroll
    for (int k = 0; k < 8; ++k) { int i = base + k; if (i < n) s += cnt[i]; }
    __shared__ int red[256];
    red[threadIdx.x] = s;
    __syncthreads();
    for (int off = 128; off > 0; off >>= 1) {
        if (threadIdx.x < off) red[threadIdx.x] += red[threadIdx.x + off];
        __syncthreads();
    }
    if (threadIdx.x == 0) blocksum[blockIdx.x] = red[0];
}

__global__ __launch_bounds__(1024) void scan_blocksums_kernel(
    int* __restrict__ blocksum, int nb, int n, int* __restrict__ row_start)
{
    __shared__ int sums[1024];
    int t = threadIdx.x;
    int v = (t < nb) ? blocksum[t] : 0;
    sums[t] = v;
    __syncthreads();
    for (int off = 1; off < 1024; off <<= 1) {
        int u = (t >= off) ? sums[t - off] : 0;
        __syncthreads();
        sums[t] += u;
        __syncthreads();
    }
    if (t < nb) blocksum[t] = sums[t] - v;
    if (t == 1023) row_start[n] = sums[1023];
}

__global__ __launch_bounds__(256) void scan_final_kernel(
    const int* __restrict__ cnt, int n, const int* __restrict__ blocksum,
    int* __restrict__ row_start, int* __restrict__ cursor)
{
    int t = threadIdx.x;
    int base = blockIdx.x * SCAN_TILE + t * 8;
    int loc[8]; int s = 0;
    #pragma unroll
    for (int k = 0; k < 8; ++k) { int i = base + k; loc[k] = (i < n) ? cnt[i] : 0; s += loc[k]; }
    __shared__ int sums[256];
    sums[t] = s;
    __syncthreads();
    for (int off = 1; off < 256; off <<= 1) {
        int u = (t >= off) ? sums[t - off] : 0;
        __syncthreads();
        sums[t] += u;
        __syncthreads();
    }
    int run = blocksum[blockIdx.x] + sums[t] - s;
    #pragma unroll
    for (int k = 0; k < 8; ++k) {
        int i = base + k;
        if (i < n) { row_start[i] = run; cursor[i] = run; run += loc[k]; }
    }
}

// fill: build perm (elist), inverse perm (ipos), and permuted sender/receiver
__global__ __launch_bounds__(256) void fill_kernel(
    const int* __restrict__ recv, const int* __restrict__ send, int n_edges,
    int* __restrict__ cursor, int* __restrict__ elist, int* __restrict__ ipos,
    int* __restrict__ s_perm, int* __restrict__ r_perm)
{
    int e = blockIdx.x * blockDim.x + threadIdx.x;
    if (e >= n_edges) return;
    int r = recv[e];
    int pos = atomicAdd(&cursor[r], 1);
    elist[pos] = e;
    ipos[e] = pos;
    s_perm[pos] = send[e];
    r_perm[pos] = r;
}

// ------- edge update on PERMUTED ef: sequential ef row, sorted receiver, random sender -------
__global__ __launch_bounds__(256) void edge_update_kernel(
    const float* __restrict__ nf, unsigned short* __restrict__ ef,
    const unsigned short* __restrict__ raw_edges, const int* __restrict__ elist,
    int use_enc,
    const int* __restrict__ s_perm, const int* __restrict__ r_perm, int n_edges,
    const float* __restrict__ W1, const float* __restrict__ b1,
    const float* __restrict__ W2, const float* __restrict__ b2,
    const float* __restrict__ eW1, const float* __restrict__ eb1,
    const float* __restrict__ eW2, const float* __restrict__ eb2)
{
    int pos = blockIdx.x * blockDim.x + threadIdx.x;
    if (pos >= n_edges) return;
    int s = s_perm[pos], r = r_perm[pos];

    float h[H];
    #pragma unroll
    for (int o = 0; o < H; ++o) h[o] = b1[o];

    // sender features (random gather, L2/L3-resident nf)
    const float4* ps = (const float4*)(nf + (size_t)s * H);
    #pragma unroll
    for (int q = 0; q < 4; ++q) {
        float4 v = ps[q];
        int k = q * 4;
        #pragma unroll
        for (int o = 0; o < H; ++o)
            h[o] += W1[o*48 + k] * v.x + W1[o*48 + k+1] * v.y
                  + W1[o*48 + k+2] * v.z + W1[o*48 + k+3] * v.w;
    }
    // receiver features (sorted: consecutive pos share r -> cache-line-hot)
    const float4* pr = (const float4*)(nf + (size_t)r * H);
    #pragma unroll
    for (int q = 0; q < 4; ++q) {
        float4 v = pr[q];
        int k = 16 + q * 4;
        #pragma unroll
        for (int o = 0; o < H; ++o)
            h[o] += W1[o*48 + k] * v.x + W1[o*48 + k+1] * v.y
                  + W1[o*48 + k+2] * v.z + W1[o*48 + k+3] * v.w;
    }
    // edge features: fused encoder (round 0) or sequential bf16 ef row
    float xe[H];
    if (use_enc) {
        int e = elist[pos];
        float v = bf2f(raw_edges[e]);
        float t[H];
        #pragma unroll
        for (int o = 0; o < H; ++o) {
            float tt = eW1[o] * v + eb1[o];
            t[o] = tt > 0.f ? tt : 0.f;
        }
        #pragma unroll
        for (int o = 0; o < H; ++o) {
            float a = eb2[o];
            #pragma unroll
            for (int k = 0; k < H; ++k) a += eW2[o * H + k] * t[k];
            xe[o] = a;
        }
    } else {
        const uint4* pe = (const uint4*)(ef + (size_t)pos * H);
        uint4 u0 = pe[0], u1 = pe[1];
        unpack8(u0, xe);
        unpack8(u1, xe + 8);
    }
    #pragma unroll
    for (int k = 0; k < H; ++k) {
        float xk = xe[k];
        #pragma unroll
        for (int o = 0; o < H; ++o) h[o] += W1[o*48 + 32 + k] * xk;
    }
    #pragma unroll
    for (int o = 0; o < H; ++o) h[o] = h[o] > 0.f ? h[o] : 0.f;

    float acc[H];
    #pragma unroll
    for (int o = 0; o < H; ++o) acc[o] = b2[o];
    #pragma unroll
    for (int k = 0; k < H; ++k) {
        float hk = h[k];
        #pragma unroll
        for (int o = 0; o < H; ++o) acc[o] += W2[o * H + k] * hk;
    }
    uint4 o0, o1;
    o0.x = packbf2(acc[0], acc[1]);  o0.y = packbf2(acc[2], acc[3]);
    o0.z = packbf2(acc[4], acc[5]);  o0.w = packbf2(acc[6], acc[7]);
    o1.x = packbf2(acc[8], acc[9]);  o1.y = packbf2(acc[10], acc[11]);
    o1.z = packbf2(acc[12], acc[13]); o1.w = packbf2(acc[14], acc[15]);
    uint4* dst = (uint4*)(ef + (size_t)pos * H);
    dst[0] = o0; dst[1] = o1;
}

// ---------------- node update: CONTIGUOUS segment of ef_perm, then MLP ----------------
__global__ __launch_bounds__(256) void node_update_kernel(
    float* __restrict__ nf, const unsigned short* __restrict__ ef,
    const int* __restrict__ row_start, int n_nodes,
    const float* __restrict__ W1, const float* __restrict__ b1,
    const float* __restrict__ W2, const float* __restrict__ b2)
{
    int i = blockIdx.x * blockDim.x + threadIdx.x;
    if (i >= n_nodes) return;
    int lo = row_start[i], hi = row_start[i + 1];
    float a[H];
    #pragma unroll
    for (int o = 0; o < H; ++o) a[o] = 0.f;
    for (int j = lo; j < hi; ++j) {
        const uint4* pe = (const uint4*)(ef + (size_t)j * H);
        uint4 u0 = pe[0], u1 = pe[1];
        float f[H];
        unpack8(u0, f);
        unpack8(u1, f + 8);
        #pragma unroll
        for (int o = 0; o < H; ++o) a[o] += f[o];
    }
    int d = hi - lo;
    float rd = 1.0f / (float)(d > 1 ? d : 1);

    float h[H];
    #pragma unroll
    for (int o = 0; o < H; ++o) h[o] = b1[o];
    const float4* pn = (const float4*)(nf + (size_t)i * H);
    #pragma unroll
    for (int q = 0; q < 4; ++q) {
        float4 v = pn[q];
        int k = q * 4;
        #pragma unroll
        for (int o = 0; o < H; ++o)
            h[o] += W1[o*32 + k] * v.x + W1[o*32 + k+1] * v.y
                  + W1[o*32 + k+2] * v.z + W1[o*32 + k+3] * v.w;
    }
    #pragma unroll
    for (int k = 0; k < H; ++k) {
        float xk = a[k] * rd;
        #pragma unroll
        for (int o = 0; o < H; ++o) h[o] += W1[o*32 + 16 + k] * xk;
    }
    #pragma unroll
    for (int o = 0; o < H; ++o) h[o] = h[o] > 0.f ? h[o] : 0.f;
    float acc[H];
    #pragma unroll
    for (int o = 0; o < H; ++o) acc[o] = b2[o];
    #pragma unroll
    for (int k = 0; k < H; ++k) {
        float hk = h[k];
        #pragma unroll
        for (int o = 0; o < H; ++o) acc[o] += W2[o * H + k] * hk;
    }
    float4* dst = (float4*)(nf + (size_t)i * H);
    dst[0] = make_float4(acc[0], acc[1], acc[2], acc[3]);
    dst[1] = make_float4(acc[4], acc[5], acc[6], acc[7]);
    dst[2] = make_float4(acc[8], acc[9], acc[10], acc[11]);
    dst[3] = make_float4(acc[12], acc[13], acc[14], acc[15]);
}

// ---------------- bidirectional edge averaging (in place, via ipos) ----------------
__global__ __launch_bounds__(256) void bi_avg_kernel(
    unsigned short* __restrict__ ef, const int* __restrict__ ipos,
    const int* __restrict__ bi, int n_bi)
{
    int p = blockIdx.x * blockDim.x + threadIdx.x;
    if (p >= n_bi) return;
    int i = ipos[bi[p]], j = ipos[bi[n_bi + p]];
    uint4* pi = (uint4*)(ef + (size_t)i * H);
    uint4* pj = (uint4*)(ef + (size_t)j * H);
    uint4 a0 = pi[0], a1 = pi[1], b0 = pj[0], b1 = pj[1];
    float fa[H], fb[H];
    unpack8(a0, fa); unpack8(a1, fa + 8);
    unpack8(b0, fb); unpack8(b1, fb + 8);
    float m[H];
    #pragma unroll
    for (int o = 0; o < H; ++o) m[o] = 0.5f * (fa[o] + fb[o]);
    uint4 o0, o1;
    o0.x = packbf2(m[0], m[1]);  o0.y = packbf2(m[2], m[3]);
    o0.z = packbf2(m[4], m[5]);  o0.w = packbf2(m[6], m[7]);
    o1.x = packbf2(m[8], m[9]);  o1.y = packbf2(m[10], m[11]);
    o1.z = packbf2(m[12], m[13]); o1.w = packbf2(m[14], m[15]);
    pi[0] = o0; pi[1] = o1;
    pj[0] = o0; pj[1] = o1;
}

// ---------------- decoder: h -> h -> 1, tril mask, emit f32 outputs ----------------
__global__ __launch_bounds__(256) void decode_kernel(
    const unsigned short* __restrict__ ef, const int* __restrict__ ipos,
    const int* __restrict__ recv, const int* __restrict__ send, int n_edges,
    const float* __restrict__ W1, const float* __restrict__ b1,
    const float* __restrict__ W2, const float* __restrict__ b2,
    float* __restrict__ out)
{
    int e = blockIdx.x * blockDim.x + threadIdx.x;
    if (e >= n_edges) return;
    int pos = ipos[e];
    const uint4* pe = (const uint4*)(ef + (size_t)pos * H);
    uint4 u0 = pe[0], u1 = pe[1];
    float x[H];
    unpack8(u0, x);
    unpack8(u1, x + 8);
    float h[H];
    #pragma unroll
    for (int o = 0; o < H; ++o) h[o] = b1[o];
    #pragma unroll
    for (int k = 0; k < H; ++k) {
        float xk = x[k];
        #pragma unroll
        for (int o = 0; o < H; ++o) h[o] += W1[o * H + k] * xk;
    }
    float val = b2[0];
    #pragma unroll
    for (int k = 0; k < H; ++k) {
        float hk = h[k] > 0.f ? h[k] : 0.f;
        val += W2[k] * hk;
    }
    int r = recv[e], s = send[e];
    val = (r >= s) ? val : 0.0f;
    out[e] = val;
    out[(size_t)n_edges + e] = bf2f(f2bf((float)r));
    out[2 * (size_t)n_edges + e] = bf2f(f2bf((float)s));
}

// ---------------- host launcher ----------------
extern "C" void kernel_launch(void* const* d_in, const int* in_sizes, int n_in,
                              void* d_out, int out_size, void* d_ws, size_t ws_size,
                              hipStream_t stream) {
    const unsigned short* nodes = (const unsigned short*)d_in[0];
    const unsigned short* edges = (const unsigned short*)d_in[1];
    const int* receivers = (const int*)d_in[2];
    const int* senders   = (const int*)d_in[3];
    const int* bi        = (const int*)d_in[4];
    const int n_nodes = in_sizes[0];
    const int n_edges = in_sizes[1];
    const int n_bi    = in_sizes[4] / 2;

    static const int wl[NW] = {16,16,256,16, 16,16,256,16,
                               3840,80,1280,80, 2560,80,1280,80,
                               256,16,16,1};
    WPtrs wp;
    {
        int off = 0;
        for (int a = 0; a < NW; ++a) {
            wp.src[a] = (const unsigned short*)d_in[5 + a];
            wp.len[a] = wl[a];
            wp.off[a] = off;
            off += wl[a];
        }
    }
    float* wf = (float*)d_ws;
    const float* Wf[NW];
    for (int a = 0; a < NW; ++a) Wf[a] = wf + wp.off[a];

    float* nf = wf + 10240;                                  // [n_nodes][16] f32
    unsigned short* ef = (unsigned short*)(nf + (size_t)n_nodes * H);  // [n_edges][16] bf16, PERMUTED
    int* cnt       = (int*)(ef + (size_t)n_edges * H);       // [n_nodes]
    int* row_start = cnt + n_nodes;                          // [n_nodes+1]
    int* cursor    = row_start + n_nodes + 1;                // [n_nodes]
    int* elist     = cursor + n_nodes;                       // [n_edges]
    int* ipos      = elist + n_edges;                        // [n_edges]
    int* s_perm    = ipos + n_edges;                         // [n_edges]
    int* r_perm    = s_perm + n_edges;                       // [n_edges]
    int* blocksum  = r_perm + n_edges;                       // [<=1024]

    const int bn = 256;
    const int nb_scan = (n_nodes + SCAN_TILE - 1) / SCAN_TILE;

    cvt_weights_kernel<<<NW, 256, 0, stream>>>(wp, wf);
    encode_kernel<<<(n_nodes + bn - 1) / bn, bn, 0, stream>>>(
        nodes, n_nodes, Wf[0], Wf[1], Wf[2], Wf[3], nf);

    // CSR build (once per launch; receivers are fixed input)
    hipMemsetAsync(cnt, 0, (size_t)n_nodes * 4, stream);
    hist_kernel<<<(n_edges + bn - 1) / bn, bn, 0, stream>>>(receivers, n_edges, cnt);
    scan_part_kernel<<<nb_scan, 256, 0, stream>>>(cnt, n_nodes, blocksum);
    scan_blocksums_kernel<<<1, 1024, 0, stream>>>(blocksum, nb_scan, n_nodes, row_start);
    scan_final_kernel<<<nb_scan, 256, 0, stream>>>(cnt, n_nodes, blocksum, row_start, cursor);
    fill_kernel<<<(n_edges + bn - 1) / bn, bn, 0, stream>>>(
        receivers, senders, n_edges, cursor, elist, ipos, s_perm, r_perm);

    for (int r = 0; r < 5; ++r) {
        edge_update_kernel<<<(n_edges + bn - 1) / bn, bn, 0, stream>>>(
            nf, ef, edges, elist, (r == 0) ? 1 : 0,
            s_perm, r_perm, n_edges,
            Wf[8] + r * 3 * H * H, Wf[9] + r * H,
            Wf[10] + r * H * H,    Wf[11] + r * H,
            Wf[4], Wf[5], Wf[6], Wf[7]);
        node_update_kernel<<<(n_nodes + bn - 1) / bn, bn, 0, stream>>>(
            nf, ef, row_start, n_nodes,
            Wf[12] + r * 2 * H * H, Wf[13] + r * H,
            Wf[14] + r * H * H,     Wf[15] + r * H);
    }

    bi_avg_kernel<<<(n_bi + bn - 1) / bn, bn, 0, stream>>>(ef, ipos, bi, n_bi);
    decode_kernel<<<(n_edges + bn - 1) / bn, bn, 0, stream>>>(
        ef, ipos, receivers, senders, n_edges,
        Wf[16], Wf[17], Wf[18], Wf[19], (float*)d_out);
}

// Round 7
// 514.739 us; speedup vs baseline: 1.7011x; 1.5785x over previous
//
#include <hip/hip_runtime.h>
#include <hip/hip_bf16.h>

#define H 16
#define NW 20
#define SCAN_TILE 2048  // 256 threads * 8 elems

typedef __attribute__((ext_vector_type(8))) short short8;
typedef __attribute__((ext_vector_type(4))) float f32x4;

__device__ __forceinline__ float bf2f(unsigned short u) {
    union { unsigned int u; float f; } c; c.u = ((unsigned int)u) << 16; return c.f;
}

// round-to-nearest-even f32 -> bf16 bits
__device__ __forceinline__ unsigned short f2bf(float f) {
    union { float f; unsigned int u; } c; c.f = f;
    unsigned int u = c.u;
    unsigned int r = (u + 0x7fffu + ((u >> 16) & 1u)) >> 16;
    return (unsigned short)r;
}

__device__ __forceinline__ unsigned int packbf2(float a, float b) {
    return (unsigned int)f2bf(a) | ((unsigned int)f2bf(b) << 16);
}

// unpack 8 bf16 (uint4) -> 8 floats, element order preserved
__device__ __forceinline__ void unpack8(uint4 u, float* f) {
    union { unsigned int u; float f; } c;
    c.u = u.x << 16; f[0] = c.f; c.u = u.x & 0xffff0000u; f[1] = c.f;
    c.u = u.y << 16; f[2] = c.f; c.u = u.y & 0xffff0000u; f[3] = c.f;
    c.u = u.z << 16; f[4] = c.f; c.u = u.z & 0xffff0000u; f[5] = c.f;
    c.u = u.w << 16; f[6] = c.f; c.u = u.w & 0xffff0000u; f[7] = c.f;
}

// ---------------- weight conversion: bf16 -> f32 staging ----------------
struct WPtrs { const unsigned short* src[NW]; int len[NW]; int off[NW]; };

__global__ void cvt_weights_kernel(WPtrs p, float* __restrict__ dst) {
    int a = blockIdx.x;
    const unsigned short* s = p.src[a];
    float* d = dst + p.off[a];
    int n = p.len[a];
    for (int t = threadIdx.x; t < n; t += blockDim.x) d[t] = bf2f(s[t]);
}

// ---- MFMA A-fragment precompute for edge-MLP weights (bf16 bit copy + zero pad) ----
// w1a: [5 rounds][2 chunks][64 lanes][8]  A[m=lane&15][k=chunk*32+quad*8+j], k<48 else 0
// w2a: [5 rounds][64 lanes][8]            A[m][k=quad*8+j], k<16 else 0
__global__ void mk_frags_kernel(const unsigned short* __restrict__ W1raw,
                                const unsigned short* __restrict__ W2raw,
                                unsigned short* __restrict__ w1a,
                                unsigned short* __restrict__ w2a)
{
    for (int idx = threadIdx.x; idx < 5 * 2 * 64 * 8; idx += blockDim.x) {
        int j = idx & 7, l = (idx >> 3) & 63, c = (idx >> 9) & 1, r = idx >> 10;
        int m = l & 15, quad = l >> 4;
        int k = c * 32 + quad * 8 + j;
        w1a[idx] = (k < 48) ? W1raw[(r * 16 + m) * 48 + k] : (unsigned short)0;
    }
    for (int idx = threadIdx.x; idx < 5 * 64 * 8; idx += blockDim.x) {
        int j = idx & 7, l = (idx >> 3) & 63, r = idx >> 9;
        int m = l & 15, quad = l >> 4;
        int k = quad * 8 + j;
        w2a[idx] = (k < 16) ? W2raw[(r * 16 + m) * 16 + k] : (unsigned short)0;
    }
}

// ---------------- node encoder: scalar -> h -> h MLP (bf16 out) ----------------
__global__ __launch_bounds__(256) void encode_node_kernel(
    const unsigned short* __restrict__ xin, int n,
    const float* __restrict__ W1, const float* __restrict__ b1,
    const float* __restrict__ W2, const float* __restrict__ b2,
    unsigned short* __restrict__ out)
{
    int i = blockIdx.x * blockDim.x + threadIdx.x;
    if (i >= n) return;
    float v = bf2f(xin[i]);
    float h[H];
    #pragma unroll
    for (int o = 0; o < H; ++o) {
        float t = W1[o] * v + b1[o];
        h[o] = t > 0.f ? t : 0.f;
    }
    float acc[H];
    #pragma unroll
    for (int o = 0; o < H; ++o) acc[o] = b2[o];
    #pragma unroll
    for (int k = 0; k < H; ++k) {
        float hk = h[k];
        #pragma unroll
        for (int o = 0; o < H; ++o) acc[o] += W2[o * H + k] * hk;
    }
    uint4 o0, o1;
    o0.x = packbf2(acc[0], acc[1]);  o0.y = packbf2(acc[2], acc[3]);
    o0.z = packbf2(acc[4], acc[5]);  o0.w = packbf2(acc[6], acc[7]);
    o1.x = packbf2(acc[8], acc[9]);  o1.y = packbf2(acc[10], acc[11]);
    o1.z = packbf2(acc[12], acc[13]); o1.w = packbf2(acc[14], acc[15]);
    uint4* dst = (uint4*)(out + (size_t)i * H);
    dst[0] = o0; dst[1] = o1;
}

// ------- edge encoder, writing ef in receiver-sorted (permuted) order -------
__global__ __launch_bounds__(256) void encode_edge_kernel(
    const unsigned short* __restrict__ edges, const int* __restrict__ elist, int n_edges,
    const float* __restrict__ W1, const float* __restrict__ b1,
    const float* __restrict__ W2, const float* __restrict__ b2,
    unsigned short* __restrict__ efb)
{
    int pos = blockIdx.x * blockDim.x + threadIdx.x;
    if (pos >= n_edges) return;
    float v = bf2f(edges[elist[pos]]);
    float h[H];
    #pragma unroll
    for (int o = 0; o < H; ++o) {
        float t = W1[o] * v + b1[o];
        h[o] = t > 0.f ? t : 0.f;
    }
    float acc[H];
    #pragma unroll
    for (int o = 0; o < H; ++o) acc[o] = b2[o];
    #pragma unroll
    for (int k = 0; k < H; ++k) {
        float hk = h[k];
        #pragma unroll
        for (int o = 0; o < H; ++o) acc[o] += W2[o * H + k] * hk;
    }
    uint4 o0, o1;
    o0.x = packbf2(acc[0], acc[1]);  o0.y = packbf2(acc[2], acc[3]);
    o0.z = packbf2(acc[4], acc[5]);  o0.w = packbf2(acc[6], acc[7]);
    o1.x = packbf2(acc[8], acc[9]);  o1.y = packbf2(acc[10], acc[11]);
    o1.z = packbf2(acc[12], acc[13]); o1.w = packbf2(acc[14], acc[15]);
    uint4* dst = (uint4*)(efb + (size_t)pos * H);
    dst[0] = o0; dst[1] = o1;
}

// ---------------- CSR build: histogram -> 3-pass scan -> fill ----------------
__global__ __launch_bounds__(256) void hist_kernel(
    const int* __restrict__ recv, int n_edges, int* __restrict__ cnt)
{
    int e = blockIdx.x * blockDim.x + threadIdx.x;
    if (e < n_edges) atomicAdd(&cnt[recv[e]], 1);
}

__global__ __launch_bounds__(256) void scan_part_kernel(
    const int* __restrict__ cnt, int n, int* __restrict__ blocksum)
{
    int base = blockIdx.x * SCAN_TILE + threadIdx.x * 8;
    int s = 0;
    #pragma unroll
    for (int k = 0; k < 8; ++k) { int i = base + k; if (i < n) s += cnt[i]; }
    __shared__ int red[256];
    red[threadIdx.x] = s;
    __syncthreads();
    for (int off = 128; off > 0; off >>= 1) {
        if (threadIdx.x < off) red[threadIdx.x] += red[threadIdx.x + off];
        __syncthreads();
    }
    if (threadIdx.x == 0) blocksum[blockIdx.x] = red[0];
}

__global__ __launch_bounds__(1024) void scan_blocksums_kernel(
    int* __restrict__ blocksum, int nb, int n, int* __restrict__ row_start)
{
    __shared__ int sums[1024];
    int t = threadIdx.x;
    int v = (t < nb) ? blocksum[t] : 0;
    sums[t] = v;
    __syncthreads();
    for (int off = 1; off < 1024; off <<= 1) {
        int u = (t >= off) ? sums[t - off] : 0;
        __syncthreads();
        sums[t] += u;
        __syncthreads();
    }
    if (t < nb) blocksum[t] = sums[t] - v;
    if (t == 1023) row_start[n] = sums[1023];
}

__global__ __launch_bounds__(256) void scan_final_kernel(
    const int* __restrict__ cnt, int n, const int* __restrict__ blocksum,
    int* __restrict__ row_start, int* __restrict__ cursor)
{
    int t = threadIdx.x;
    int base = blockIdx.x * SCAN_TILE + t * 8;
    int loc[8]; int s = 0;
    #pragma unroll
    for (int k = 0; k < 8; ++k) { int i = base + k; loc[k] = (i < n) ? cnt[i] : 0; s += loc[k]; }
    __shared__ int sums[256];
    sums[t] = s;
    __syncthreads();
    for (int off = 1; off < 256; off <<= 1) {
        int u = (t >= off) ? sums[t - off] : 0;
        __syncthreads();
        sums[t] += u;
        __syncthreads();
    }
    int run = blocksum[blockIdx.x] + sums[t] - s;
    #pragma unroll
    for (int k = 0; k < 8; ++k) {
        int i = base + k;
        if (i < n) { row_start[i] = run; cursor[i] = run; run += loc[k]; }
    }
}

__global__ __launch_bounds__(256) void fill_kernel(
    const int* __restrict__ recv, const int* __restrict__ send, int n_edges,
    int* __restrict__ cursor, int* __restrict__ elist, int* __restrict__ ipos,
    int* __restrict__ s_perm, int* __restrict__ r_perm)
{
    int e = blockIdx.x * blockDim.x + threadIdx.x;
    if (e >= n_edges) return;
    int r = recv[e];
    int pos = atomicAdd(&cursor[r], 1);
    elist[pos] = e;
    ipos[e] = pos;
    s_perm[pos] = send[e];
    r_perm[pos] = r;
}

// ======== MFMA edge update: per block 256 edges, D = W2·relu(W1·X + b1) + b2 ========
// X (K=48 zero-padded to 64) staged in LDS granule-major: granule g (8 bf16 of K),
// entry [g*256 + n_local] (uint4). B-frag read: lane(n=lane&15, quad) reads granule
// (chunk*4+quad) at its edge column -> short8. C/D layout: col=lane&15, row=quad*4+reg.
__global__ __launch_bounds__(256) void edge_update_mfma(
    const unsigned short* __restrict__ nfb, unsigned short* __restrict__ efb,
    const int* __restrict__ s_perm, const int* __restrict__ r_perm, int n_edges,
    const unsigned short* __restrict__ w1a, const unsigned short* __restrict__ w2a,
    const float* __restrict__ b1, const float* __restrict__ b2)
{
    __shared__ uint4 Xs[8 * 256];   // 32 KB
    __shared__ uint4 Hs[4 * 4 * 16]; // 4 KB: [wave][granule][n]

    const int t = threadIdx.x;
    const int lane = t & 63;
    const int wave = t >> 6;
    const int quad = lane >> 4;
    const int nn = lane & 15;
    const int base = blockIdx.x * 256;

    // ---- per-lane constant fragments ----
    const short8 wa0 = *(const short8*)(w1a + (size_t)lane * 8);          // W1 k 0..31
    const short8 wa1 = *(const short8*)(w1a + 512 + (size_t)lane * 8);    // W1 k 32..63
    const short8 wa2 = *(const short8*)(w2a + (size_t)lane * 8);          // W2 k 0..31
    const float4 bv1 = *(const float4*)(b1 + quad * 4);
    const float4 bv2 = *(const float4*)(b2 + quad * 4);

    // ---- stage X for 256 edges ----
    int pos = base + t;
    int cp = pos < n_edges ? pos : n_edges - 1;
    int s = s_perm[cp], r = r_perm[cp];
    const uint4* pns = (const uint4*)(nfb + (size_t)s * H);
    const uint4* pnr = (const uint4*)(nfb + (size_t)r * H);
    const uint4* pef = (const uint4*)(efb + (size_t)cp * H);
    uint4 a0 = pns[0], a1 = pns[1];
    uint4 r0 = pnr[0], r1 = pnr[1];
    uint4 c0 = pef[0], c1 = pef[1];
    uint4 z; z.x = 0; z.y = 0; z.z = 0; z.w = 0;
    Xs[0 * 256 + t] = a0; Xs[1 * 256 + t] = a1;   // k  0..15 : nf[sender]
    Xs[2 * 256 + t] = r0; Xs[3 * 256 + t] = r1;   // k 16..31 : nf[receiver]
    Xs[4 * 256 + t] = c0; Xs[5 * 256 + t] = c1;   // k 32..47 : ef
    Xs[6 * 256 + t] = z;  Xs[7 * 256 + t] = z;    // k 48..63 : zero pad
    if (lane < 32) Hs[wave * 64 + 32 + lane] = z; // h zero pad k 16..31
    __syncthreads();

    #pragma unroll
    for (int it = 0; it < 4; ++it) {
        int nb = it * 64 + wave * 16 + nn;        // block-local edge for this lane col
        const short8 xb0 = *(const short8*)&Xs[quad * 256 + nb];
        const short8 xb1 = *(const short8*)&Xs[(4 + quad) * 256 + nb];
        f32x4 d1 = {0.f, 0.f, 0.f, 0.f};
        d1 = __builtin_amdgcn_mfma_f32_16x16x32_bf16(wa0, xb0, d1, 0, 0, 0);
        d1 = __builtin_amdgcn_mfma_f32_16x16x32_bf16(wa1, xb1, d1, 0, 0, 0);
        float h0 = d1[0] + bv1.x; h0 = h0 > 0.f ? h0 : 0.f;
        float h1 = d1[1] + bv1.y; h1 = h1 > 0.f ? h1 : 0.f;
        float h2 = d1[2] + bv1.z; h2 = h2 > 0.f ? h2 : 0.f;
        float h3 = d1[3] + bv1.w; h3 = h3 > 0.f ? h3 : 0.f;
        uint2 hu;
        hu.x = packbf2(h0, h1);
        hu.y = packbf2(h2, h3);
        // rows quad*4..+3 of column nn -> h granule quad>>1, half quad&1
        ((uint2*)Hs)[(wave * 64 + (quad >> 1) * 16 + nn) * 2 + (quad & 1)] = hu;
        __syncthreads();
        const short8 hb = *(const short8*)&Hs[wave * 64 + quad * 16 + nn];
        f32x4 d2 = {0.f, 0.f, 0.f, 0.f};
        d2 = __builtin_amdgcn_mfma_f32_16x16x32_bf16(wa2, hb, d2, 0, 0, 0);
        int edge = base + nb;
        if (edge < n_edges) {
            uint2 ov;
            ov.x = packbf2(d2[0] + bv2.x, d2[1] + bv2.y);
            ov.y = packbf2(d2[2] + bv2.z, d2[3] + bv2.w);
            ((uint2*)efb)[(size_t)edge * 4 + quad] = ov;
        }
        __syncthreads();
    }
}

// ---------------- node update: contiguous ef_perm segment + MLP (bf16 nf) ----------------
__global__ __launch_bounds__(256) void node_update_kernel(
    unsigned short* __restrict__ nfb, const unsigned short* __restrict__ ef,
    const int* __restrict__ row_start, int n_nodes,
    const float* __restrict__ W1, const float* __restrict__ b1,
    const float* __restrict__ W2, const float* __restrict__ b2)
{
    int i = blockIdx.x * blockDim.x + threadIdx.x;
    if (i >= n_nodes) return;
    int lo = row_start[i], hi = row_start[i + 1];
    float a[H];
    #pragma unroll
    for (int o = 0; o < H; ++o) a[o] = 0.f;
    for (int j = lo; j < hi; ++j) {
        const uint4* pe = (const uint4*)(ef + (size_t)j * H);
        uint4 u0 = pe[0], u1 = pe[1];
        float f[H];
        unpack8(u0, f);
        unpack8(u1, f + 8);
        #pragma unroll
        for (int o = 0; o < H; ++o) a[o] += f[o];
    }
    int d = hi - lo;
    float rd = 1.0f / (float)(d > 1 ? d : 1);

    const uint4* pn = (const uint4*)(nfb + (size_t)i * H);
    uint4 n0 = pn[0], n1 = pn[1];
    float xn[H];
    unpack8(n0, xn);
    unpack8(n1, xn + 8);

    float h[H];
    #pragma unroll
    for (int o = 0; o < H; ++o) h[o] = b1[o];
    #pragma unroll
    for (int k = 0; k < H; ++k) {
        float xk = xn[k];
        #pragma unroll
        for (int o = 0; o < H; ++o) h[o] += W1[o * 32 + k] * xk;
    }
    #pragma unroll
    for (int k = 0; k < H; ++k) {
        float xk = a[k] * rd;
        #pragma unroll
        for (int o = 0; o < H; ++o) h[o] += W1[o * 32 + 16 + k] * xk;
    }
    #pragma unroll
    for (int o = 0; o < H; ++o) h[o] = h[o] > 0.f ? h[o] : 0.f;
    float acc[H];
    #pragma unroll
    for (int o = 0; o < H; ++o) acc[o] = b2[o];
    #pragma unroll
    for (int k = 0; k < H; ++k) {
        float hk = h[k];
        #pragma unroll
        for (int o = 0; o < H; ++o) acc[o] += W2[o * H + k] * hk;
    }
    uint4 o0, o1;
    o0.x = packbf2(acc[0], acc[1]);  o0.y = packbf2(acc[2], acc[3]);
    o0.z = packbf2(acc[4], acc[5]);  o0.w = packbf2(acc[6], acc[7]);
    o1.x = packbf2(acc[8], acc[9]);  o1.y = packbf2(acc[10], acc[11]);
    o1.z = packbf2(acc[12], acc[13]); o1.w = packbf2(acc[14], acc[15]);
    uint4* dst = (uint4*)(nfb + (size_t)i * H);
    dst[0] = o0; dst[1] = o1;
}

// ---------------- bidirectional edge averaging (in place, via ipos) ----------------
__global__ __launch_bounds__(256) void bi_avg_kernel(
    unsigned short* __restrict__ ef, const int* __restrict__ ipos,
    const int* __restrict__ bi, int n_bi)
{
    int p = blockIdx.x * blockDim.x + threadIdx.x;
    if (p >= n_bi) return;
    int i = ipos[bi[p]], j = ipos[bi[n_bi + p]];
    uint4* pi = (uint4*)(ef + (size_t)i * H);
    uint4* pj = (uint4*)(ef + (size_t)j * H);
    uint4 a0 = pi[0], a1 = pi[1], b0 = pj[0], b1 = pj[1];
    float fa[H], fb[H];
    unpack8(a0, fa); unpack8(a1, fa + 8);
    unpack8(b0, fb); unpack8(b1, fb + 8);
    float m[H];
    #pragma unroll
    for (int o = 0; o < H; ++o) m[o] = 0.5f * (fa[o] + fb[o]);
    uint4 o0, o1;
    o0.x = packbf2(m[0], m[1]);  o0.y = packbf2(m[2], m[3]);
    o0.z = packbf2(m[4], m[5]);  o0.w = packbf2(m[6], m[7]);
    o1.x = packbf2(m[8], m[9]);  o1.y = packbf2(m[10], m[11]);
    o1.z = packbf2(m[12], m[13]); o1.w = packbf2(m[14], m[15]);
    pi[0] = o0; pi[1] = o1;
    pj[0] = o0; pj[1] = o1;
}

// ---------------- decoder: h -> h -> 1, tril mask, emit f32 outputs ----------------
__global__ __launch_bounds__(256) void decode_kernel(
    const unsigned short* __restrict__ ef, const int* __restrict__ ipos,
    const int* __restrict__ recv, const int* __restrict__ send, int n_edges,
    const float* __restrict__ W1, const float* __restrict__ b1,
    const float* __restrict__ W2, const float* __restrict__ b2,
    float* __restrict__ out)
{
    int e = blockIdx.x * blockDim.x + threadIdx.x;
    if (e >= n_edges) return;
    int pos = ipos[e];
    const uint4* pe = (const uint4*)(ef + (size_t)pos * H);
    uint4 u0 = pe[0], u1 = pe[1];
    float x[H];
    unpack8(u0, x);
    unpack8(u1, x + 8);
    float h[H];
    #pragma unroll
    for (int o = 0; o < H; ++o) h[o] = b1[o];
    #pragma unroll
    for (int k = 0; k < H; ++k) {
        float xk = x[k];
        #pragma unroll
        for (int o = 0; o < H; ++o) h[o] += W1[o * H + k] * xk;
    }
    float val = b2[0];
    #pragma unroll
    for (int k = 0; k < H; ++k) {
        float hk = h[k] > 0.f ? h[k] : 0.f;
        val += W2[k] * hk;
    }
    int r = recv[e], s = send[e];
    val = (r >= s) ? val : 0.0f;
    out[e] = val;
    out[(size_t)n_edges + e] = bf2f(f2bf((float)r));
    out[2 * (size_t)n_edges + e] = bf2f(f2bf((float)s));
}

// ---------------- host launcher ----------------
extern "C" void kernel_launch(void* const* d_in, const int* in_sizes, int n_in,
                              void* d_out, int out_size, void* d_ws, size_t ws_size,
                              hipStream_t stream) {
    const unsigned short* nodes = (const unsigned short*)d_in[0];
    const unsigned short* edges = (const unsigned short*)d_in[1];
    const int* receivers = (const int*)d_in[2];
    const int* senders   = (const int*)d_in[3];
    const int* bi        = (const int*)d_in[4];
    const int n_nodes = in_sizes[0];
    const int n_edges = in_sizes[1];
    const int n_bi    = in_sizes[4] / 2;

    static const int wl[NW] = {16,16,256,16, 16,16,256,16,
                               3840,80,1280,80, 2560,80,1280,80,
                               256,16,16,1};
    WPtrs wp;
    {
        int off = 0;
        for (int a = 0; a < NW; ++a) {
            wp.src[a] = (const unsigned short*)d_in[5 + a];
            wp.len[a] = wl[a];
            wp.off[a] = off;
            off += wl[a];
        }
    }
    float* wf = (float*)d_ws;
    const float* Wf[NW];
    for (int a = 0; a < NW; ++a) Wf[a] = wf + wp.off[a];

    unsigned short* w1a = (unsigned short*)(wf + 10240);     // [5][2][64][8] bf16 A-frags
    unsigned short* w2a = w1a + 5 * 2 * 64 * 8;              // [5][64][8]
    unsigned short* nfb = w2a + 5 * 64 * 8;                  // [n_nodes][16] bf16
    unsigned short* efb = nfb + (size_t)n_nodes * H;         // [n_edges][16] bf16, PERMUTED
    int* cnt       = (int*)(efb + (size_t)n_edges * H);      // [n_nodes]
    int* row_start = cnt + n_nodes;                          // [n_nodes+1]
    int* cursor    = row_start + n_nodes + 1;                // [n_nodes]
    int* elist     = cursor + n_nodes;                       // [n_edges]
    int* ipos      = elist + n_edges;                        // [n_edges]
    int* s_perm    = ipos + n_edges;                         // [n_edges]
    int* r_perm    = s_perm + n_edges;                       // [n_edges]
    int* blocksum  = r_perm + n_edges;                       // [<=1024]

    const int bn = 256;
    const int nb_scan = (n_nodes + SCAN_TILE - 1) / SCAN_TILE;
    const int nb_edge = (n_edges + bn - 1) / bn;

    cvt_weights_kernel<<<NW, 256, 0, stream>>>(wp, wf);
    mk_frags_kernel<<<1, 256, 0, stream>>>(
        (const unsigned short*)d_in[13], (const unsigned short*)d_in[15], w1a, w2a);
    encode_node_kernel<<<(n_nodes + bn - 1) / bn, bn, 0, stream>>>(
        nodes, n_nodes, Wf[0], Wf[1], Wf[2], Wf[3], nfb);

    // CSR build (once per launch; receivers are fixed input)
    hipMemsetAsync(cnt, 0, (size_t)n_nodes * 4, stream);
    hist_kernel<<<nb_edge, bn, 0, stream>>>(receivers, n_edges, cnt);
    scan_part_kernel<<<nb_scan, 256, 0, stream>>>(cnt, n_nodes, blocksum);
    scan_blocksums_kernel<<<1, 1024, 0, stream>>>(blocksum, nb_scan, n_nodes, row_start);
    scan_final_kernel<<<nb_scan, 256, 0, stream>>>(cnt, n_nodes, blocksum, row_start, cursor);
    fill_kernel<<<nb_edge, bn, 0, stream>>>(
        receivers, senders, n_edges, cursor, elist, ipos, s_perm, r_perm);

    encode_edge_kernel<<<nb_edge, bn, 0, stream>>>(
        edges, elist, n_edges, Wf[4], Wf[5], Wf[6], Wf[7], efb);

    for (int r = 0; r < 5; ++r) {
        edge_update_mfma<<<nb_edge, bn, 0, stream>>>(
            nfb, efb, s_perm, r_perm, n_edges,
            w1a + r * 1024, w2a + r * 512,
            Wf[9] + r * H, Wf[11] + r * H);
        node_update_kernel<<<(n_nodes + bn - 1) / bn, bn, 0, stream>>>(
            nfb, efb, row_start, n_nodes,
            Wf[12] + r * 2 * H * H, Wf[13] + r * H,
            Wf[14] + r * H * H,     Wf[15] + r * H);
    }

    bi_avg_kernel<<<(n_bi + bn - 1) / bn, bn, 0, stream>>>(efb, ipos, bi, n_bi);
    decode_kernel<<<nb_edge, bn, 0, stream>>>(
        efb, ipos, receivers, senders, n_edges,
        Wf[16], Wf[17], Wf[18], Wf[19], (float*)d_out);
}

// Round 8
// 505.848 us; speedup vs baseline: 1.7309x; 1.0176x over previous
//
#include <hip/hip_runtime.h>
#include <hip/hip_bf16.h>

#define H 16
#define NW 20
#define SCAN_TILE 2048  // 256 threads * 8 elems

typedef __attribute__((ext_vector_type(8))) short short8;
typedef __attribute__((ext_vector_type(4))) float f32x4;

__device__ __forceinline__ float bf2f(unsigned short u) {
    union { unsigned int u; float f; } c; c.u = ((unsigned int)u) << 16; return c.f;
}

// round-to-nearest-even f32 -> bf16 bits
__device__ __forceinline__ unsigned short f2bf(float f) {
    union { float f; unsigned int u; } c; c.f = f;
    unsigned int u = c.u;
    unsigned int r = (u + 0x7fffu + ((u >> 16) & 1u)) >> 16;
    return (unsigned short)r;
}

__device__ __forceinline__ unsigned int packbf2(float a, float b) {
    return (unsigned int)f2bf(a) | ((unsigned int)f2bf(b) << 16);
}

// unpack 8 bf16 (uint4) -> 8 floats, element order preserved
__device__ __forceinline__ void unpack8(uint4 u, float* f) {
    union { unsigned int u; float f; } c;
    c.u = u.x << 16; f[0] = c.f; c.u = u.x & 0xffff0000u; f[1] = c.f;
    c.u = u.y << 16; f[2] = c.f; c.u = u.y & 0xffff0000u; f[3] = c.f;
    c.u = u.z << 16; f[4] = c.f; c.u = u.z & 0xffff0000u; f[5] = c.f;
    c.u = u.w << 16; f[6] = c.f; c.u = u.w & 0xffff0000u; f[7] = c.f;
}

// ---------------- weight conversion: bf16 -> f32 staging ----------------
struct WPtrs { const unsigned short* src[NW]; int len[NW]; int off[NW]; };

__global__ void cvt_weights_kernel(WPtrs p, float* __restrict__ dst) {
    int a = blockIdx.x;
    const unsigned short* s = p.src[a];
    float* d = dst + p.off[a];
    int n = p.len[a];
    for (int t = threadIdx.x; t < n; t += blockDim.x) d[t] = bf2f(s[t]);
}

// ---- MFMA A-fragment precompute for edge-MLP weights (bf16 bit copy + zero pad) ----
__global__ void mk_frags_kernel(const unsigned short* __restrict__ W1raw,
                                const unsigned short* __restrict__ W2raw,
                                unsigned short* __restrict__ w1a,
                                unsigned short* __restrict__ w2a)
{
    for (int idx = threadIdx.x; idx < 5 * 2 * 64 * 8; idx += blockDim.x) {
        int j = idx & 7, l = (idx >> 3) & 63, c = (idx >> 9) & 1, r = idx >> 10;
        int m = l & 15, quad = l >> 4;
        int k = c * 32 + quad * 8 + j;
        w1a[idx] = (k < 48) ? W1raw[(r * 16 + m) * 48 + k] : (unsigned short)0;
    }
    for (int idx = threadIdx.x; idx < 5 * 64 * 8; idx += blockDim.x) {
        int j = idx & 7, l = (idx >> 3) & 63, r = idx >> 9;
        int m = l & 15, quad = l >> 4;
        int k = quad * 8 + j;
        w2a[idx] = (k < 16) ? W2raw[(r * 16 + m) * 16 + k] : (unsigned short)0;
    }
}

// ---------------- node encoder: scalar -> h -> h MLP (bf16 out) ----------------
__global__ __launch_bounds__(256) void encode_node_kernel(
    const unsigned short* __restrict__ xin, int n,
    const float* __restrict__ W1, const float* __restrict__ b1,
    const float* __restrict__ W2, const float* __restrict__ b2,
    unsigned short* __restrict__ out)
{
    int i = blockIdx.x * blockDim.x + threadIdx.x;
    if (i >= n) return;
    float v = bf2f(xin[i]);
    float h[H];
    #pragma unroll
    for (int o = 0; o < H; ++o) {
        float t = W1[o] * v + b1[o];
        h[o] = t > 0.f ? t : 0.f;
    }
    float acc[H];
    #pragma unroll
    for (int o = 0; o < H; ++o) acc[o] = b2[o];
    #pragma unroll
    for (int k = 0; k < H; ++k) {
        float hk = h[k];
        #pragma unroll
        for (int o = 0; o < H; ++o) acc[o] += W2[o * H + k] * hk;
    }
    uint4 o0, o1;
    o0.x = packbf2(acc[0], acc[1]);  o0.y = packbf2(acc[2], acc[3]);
    o0.z = packbf2(acc[4], acc[5]);  o0.w = packbf2(acc[6], acc[7]);
    o1.x = packbf2(acc[8], acc[9]);  o1.y = packbf2(acc[10], acc[11]);
    o1.z = packbf2(acc[12], acc[13]); o1.w = packbf2(acc[14], acc[15]);
    uint4* dst = (uint4*)(out + (size_t)i * H);
    dst[0] = o0; dst[1] = o1;
}

// ---------------- CSR build: histogram -> 3-pass scan ----------------
__global__ __launch_bounds__(256) void hist_kernel(
    const int* __restrict__ recv, int n_edges, int* __restrict__ cnt)
{
    int e = blockIdx.x * blockDim.x + threadIdx.x;
    if (e < n_edges) atomicAdd(&cnt[recv[e]], 1);
}

__global__ __launch_bounds__(256) void scan_part_kernel(
    const int* __restrict__ cnt, int n, int* __restrict__ blocksum)
{
    int base = blockIdx.x * SCAN_TILE + threadIdx.x * 8;
    int s = 0;
    #pragma unroll
    for (int k = 0; k < 8; ++k) { int i = base + k; if (i < n) s += cnt[i]; }
    __shared__ int red[256];
    red[threadIdx.x] = s;
    __syncthreads();
    for (int off = 128; off > 0; off >>= 1) {
        if (threadIdx.x < off) red[threadIdx.x] += red[threadIdx.x + off];
        __syncthreads();
    }
    if (threadIdx.x == 0) blocksum[blockIdx.x] = red[0];
}

__global__ __launch_bounds__(1024) void scan_blocksums_kernel(
    int* __restrict__ blocksum, int nb, int n, int* __restrict__ row_start)
{
    __shared__ int sums[1024];
    int t = threadIdx.x;
    int v = (t < nb) ? blocksum[t] : 0;
    sums[t] = v;
    __syncthreads();
    for (int off = 1; off < 1024; off <<= 1) {
        int u = (t >= off) ? sums[t - off] : 0;
        __syncthreads();
        sums[t] += u;
        __syncthreads();
    }
    if (t < nb) blocksum[t] = sums[t] - v;
    if (t == 1023) row_start[n] = sums[1023];
}

__global__ __launch_bounds__(256) void scan_final_kernel(
    const int* __restrict__ cnt, int n, const int* __restrict__ blocksum,
    int* __restrict__ row_start, int* __restrict__ cursor)
{
    int t = threadIdx.x;
    int base = blockIdx.x * SCAN_TILE + t * 8;
    int loc[8]; int s = 0;
    #pragma unroll
    for (int k = 0; k < 8; ++k) { int i = base + k; loc[k] = (i < n) ? cnt[i] : 0; s += loc[k]; }
    __shared__ int sums[256];
    sums[t] = s;
    __syncthreads();
    for (int off = 1; off < 256; off <<= 1) {
        int u = (t >= off) ? sums[t - off] : 0;
        __syncthreads();
        sums[t] += u;
        __syncthreads();
    }
    int run = blocksum[blockIdx.x] + sums[t] - s;
    #pragma unroll
    for (int k = 0; k < 8; ++k) {
        int i = base + k;
        if (i < n) { row_start[i] = run; cursor[i] = run; run += loc[k]; }
    }
}

// r_perm expansion: coalesced sequential writes instead of 1M scattered stores
__global__ __launch_bounds__(256) void expand_r_kernel(
    const int* __restrict__ row_start, int n_nodes, int* __restrict__ r_perm)
{
    int i = blockIdx.x * blockDim.x + threadIdx.x;
    if (i >= n_nodes) return;
    int lo = row_start[i], hi = row_start[i + 1];
    for (int p = lo; p < hi; ++p) r_perm[p] = i;
}

// ---- fill + fused edge encoder: one scattered 32B ef row + one scattered 4B s ----
__global__ __launch_bounds__(256) void fill_encode_kernel(
    const int* __restrict__ recv, const int* __restrict__ send,
    const unsigned short* __restrict__ edges, int n_edges,
    int* __restrict__ cursor, int* __restrict__ ipos, int* __restrict__ s_perm,
    unsigned short* __restrict__ efb,
    const float* __restrict__ W1, const float* __restrict__ b1,
    const float* __restrict__ W2, const float* __restrict__ b2)
{
    int e = blockIdx.x * blockDim.x + threadIdx.x;
    if (e >= n_edges) return;
    int r = recv[e];
    int pos = atomicAdd(&cursor[r], 1);
    ipos[e] = pos;
    s_perm[pos] = send[e];

    float v = bf2f(edges[e]);
    float h[H];
    #pragma unroll
    for (int o = 0; o < H; ++o) {
        float t = W1[o] * v + b1[o];
        h[o] = t > 0.f ? t : 0.f;
    }
    float acc[H];
    #pragma unroll
    for (int o = 0; o < H; ++o) acc[o] = b2[o];
    #pragma unroll
    for (int k = 0; k < H; ++k) {
        float hk = h[k];
        #pragma unroll
        for (int o = 0; o < H; ++o) acc[o] += W2[o * H + k] * hk;
    }
    uint4 o0, o1;
    o0.x = packbf2(acc[0], acc[1]);  o0.y = packbf2(acc[2], acc[3]);
    o0.z = packbf2(acc[4], acc[5]);  o0.w = packbf2(acc[6], acc[7]);
    o1.x = packbf2(acc[8], acc[9]);  o1.y = packbf2(acc[10], acc[11]);
    o1.z = packbf2(acc[12], acc[13]); o1.w = packbf2(acc[14], acc[15]);
    uint4* dst = (uint4*)(efb + (size_t)pos * H);
    dst[0] = o0; dst[1] = o1;
}

// ======== MFMA edge update: per block 256 edges, D = W2·relu(W1·X + b1) + b2 ========
__global__ __launch_bounds__(256) void edge_update_mfma(
    const unsigned short* __restrict__ nfb, unsigned short* __restrict__ efb,
    const int* __restrict__ s_perm, const int* __restrict__ r_perm, int n_edges,
    const unsigned short* __restrict__ w1a, const unsigned short* __restrict__ w2a,
    const float* __restrict__ b1, const float* __restrict__ b2)
{
    __shared__ uint4 Xs[8 * 256];    // 32 KB
    __shared__ uint4 Hs[4 * 4 * 16]; // 4 KB: [wave][granule][n]

    const int t = threadIdx.x;
    const int lane = t & 63;
    const int wave = t >> 6;
    const int quad = lane >> 4;
    const int nn = lane & 15;
    const int base = blockIdx.x * 256;

    const short8 wa0 = *(const short8*)(w1a + (size_t)lane * 8);          // W1 k 0..31
    const short8 wa1 = *(const short8*)(w1a + 512 + (size_t)lane * 8);    // W1 k 32..63
    const short8 wa2 = *(const short8*)(w2a + (size_t)lane * 8);          // W2 k 0..31
    const float4 bv1 = *(const float4*)(b1 + quad * 4);
    const float4 bv2 = *(const float4*)(b2 + quad * 4);

    int pos = base + t;
    int cp = pos < n_edges ? pos : n_edges - 1;
    int s = s_perm[cp], r = r_perm[cp];
    const uint4* pns = (const uint4*)(nfb + (size_t)s * H);
    const uint4* pnr = (const uint4*)(nfb + (size_t)r * H);
    const uint4* pef = (const uint4*)(efb + (size_t)cp * H);
    uint4 a0 = pns[0], a1 = pns[1];
    uint4 r0 = pnr[0], r1 = pnr[1];
    uint4 c0 = pef[0], c1 = pef[1];
    uint4 z; z.x = 0; z.y = 0; z.z = 0; z.w = 0;
    Xs[0 * 256 + t] = a0; Xs[1 * 256 + t] = a1;   // k  0..15 : nf[sender]
    Xs[2 * 256 + t] = r0; Xs[3 * 256 + t] = r1;   // k 16..31 : nf[receiver]
    Xs[4 * 256 + t] = c0; Xs[5 * 256 + t] = c1;   // k 32..47 : ef
    Xs[6 * 256 + t] = z;  Xs[7 * 256 + t] = z;    // k 48..63 : zero pad
    if (lane < 32) Hs[wave * 64 + 32 + lane] = z; // h zero pad k 16..31
    __syncthreads();

    #pragma unroll
    for (int it = 0; it < 4; ++it) {
        int nb = it * 64 + wave * 16 + nn;
        const short8 xb0 = *(const short8*)&Xs[quad * 256 + nb];
        const short8 xb1 = *(const short8*)&Xs[(4 + quad) * 256 + nb];
        f32x4 d1 = {0.f, 0.f, 0.f, 0.f};
        d1 = __builtin_amdgcn_mfma_f32_16x16x32_bf16(wa0, xb0, d1, 0, 0, 0);
        d1 = __builtin_amdgcn_mfma_f32_16x16x32_bf16(wa1, xb1, d1, 0, 0, 0);
        float h0 = d1[0] + bv1.x; h0 = h0 > 0.f ? h0 : 0.f;
        float h1 = d1[1] + bv1.y; h1 = h1 > 0.f ? h1 : 0.f;
        float h2 = d1[2] + bv1.z; h2 = h2 > 0.f ? h2 : 0.f;
        float h3 = d1[3] + bv1.w; h3 = h3 > 0.f ? h3 : 0.f;
        uint2 hu;
        hu.x = packbf2(h0, h1);
        hu.y = packbf2(h2, h3);
        ((uint2*)Hs)[(wave * 64 + (quad >> 1) * 16 + nn) * 2 + (quad & 1)] = hu;
        __syncthreads();
        const short8 hb = *(const short8*)&Hs[wave * 64 + quad * 16 + nn];
        f32x4 d2 = {0.f, 0.f, 0.f, 0.f};
        d2 = __builtin_amdgcn_mfma_f32_16x16x32_bf16(wa2, hb, d2, 0, 0, 0);
        int edge = base + nb;
        if (edge < n_edges) {
            uint2 ov;
            ov.x = packbf2(d2[0] + bv2.x, d2[1] + bv2.y);
            ov.y = packbf2(d2[2] + bv2.z, d2[3] + bv2.w);
            ((uint2*)efb)[(size_t)edge * 4 + quad] = ov;
        }
        __syncthreads();
    }
}

// ---------------- node update: contiguous ef_perm segment + MLP (bf16 nf) ----------------
__global__ __launch_bounds__(256) void node_update_kernel(
    unsigned short* __restrict__ nfb, const unsigned short* __restrict__ ef,
    const int* __restrict__ row_start, int n_nodes,
    const float* __restrict__ W1, const float* __restrict__ b1,
    const float* __restrict__ W2, const float* __restrict__ b2)
{
    int i = blockIdx.x * blockDim.x + threadIdx.x;
    if (i >= n_nodes) return;
    int lo = row_start[i], hi = row_start[i + 1];
    float a[H];
    #pragma unroll
    for (int o = 0; o < H; ++o) a[o] = 0.f;
    for (int j = lo; j < hi; ++j) {
        const uint4* pe = (const uint4*)(ef + (size_t)j * H);
        uint4 u0 = pe[0], u1 = pe[1];
        float f[H];
        unpack8(u0, f);
        unpack8(u1, f + 8);
        #pragma unroll
        for (int o = 0; o < H; ++o) a[o] += f[o];
    }
    int d = hi - lo;
    float rd = 1.0f / (float)(d > 1 ? d : 1);

    const uint4* pn = (const uint4*)(nfb + (size_t)i * H);
    uint4 n0 = pn[0], n1 = pn[1];
    float xn[H];
    unpack8(n0, xn);
    unpack8(n1, xn + 8);

    float h[H];
    #pragma unroll
    for (int o = 0; o < H; ++o) h[o] = b1[o];
    #pragma unroll
    for (int k = 0; k < H; ++k) {
        float xk = xn[k];
        #pragma unroll
        for (int o = 0; o < H; ++o) h[o] += W1[o * 32 + k] * xk;
    }
    #pragma unroll
    for (int k = 0; k < H; ++k) {
        float xk = a[k] * rd;
        #pragma unroll
        for (int o = 0; o < H; ++o) h[o] += W1[o * 32 + 16 + k] * xk;
    }
    #pragma unroll
    for (int o = 0; o < H; ++o) h[o] = h[o] > 0.f ? h[o] : 0.f;
    float acc[H];
    #pragma unroll
    for (int o = 0; o < H; ++o) acc[o] = b2[o];
    #pragma unroll
    for (int k = 0; k < H; ++k) {
        float hk = h[k];
        #pragma unroll
        for (int o = 0; o < H; ++o) acc[o] += W2[o * H + k] * hk;
    }
    uint4 o0, o1;
    o0.x = packbf2(acc[0], acc[1]);  o0.y = packbf2(acc[2], acc[3]);
    o0.z = packbf2(acc[4], acc[5]);  o0.w = packbf2(acc[6], acc[7]);
    o1.x = packbf2(acc[8], acc[9]);  o1.y = packbf2(acc[10], acc[11]);
    o1.z = packbf2(acc[12], acc[13]); o1.w = packbf2(acc[14], acc[15]);
    uint4* dst = (uint4*)(nfb + (size_t)i * H);
    dst[0] = o0; dst[1] = o1;
}

// ---------------- bidirectional edge averaging (in place, via ipos) ----------------
__global__ __launch_bounds__(256) void bi_avg_kernel(
    unsigned short* __restrict__ ef, const int* __restrict__ ipos,
    const int* __restrict__ bi, int n_bi)
{
    int p = blockIdx.x * blockDim.x + threadIdx.x;
    if (p >= n_bi) return;
    int i = ipos[bi[p]], j = ipos[bi[n_bi + p]];
    uint4* pi = (uint4*)(ef + (size_t)i * H);
    uint4* pj = (uint4*)(ef + (size_t)j * H);
    uint4 a0 = pi[0], a1 = pi[1], b0 = pj[0], b1 = pj[1];
    float fa[H], fb[H];
    unpack8(a0, fa); unpack8(a1, fa + 8);
    unpack8(b0, fb); unpack8(b1, fb + 8);
    float m[H];
    #pragma unroll
    for (int o = 0; o < H; ++o) m[o] = 0.5f * (fa[o] + fb[o]);
    uint4 o0, o1;
    o0.x = packbf2(m[0], m[1]);  o0.y = packbf2(m[2], m[3]);
    o0.z = packbf2(m[4], m[5]);  o0.w = packbf2(m[6], m[7]);
    o1.x = packbf2(m[8], m[9]);  o1.y = packbf2(m[10], m[11]);
    o1.z = packbf2(m[12], m[13]); o1.w = packbf2(m[14], m[15]);
    pi[0] = o0; pi[1] = o1;
    pj[0] = o0; pj[1] = o1;
}

// ---------------- decoder: h -> h -> 1, tril mask, emit f32 outputs ----------------
__global__ __launch_bounds__(256) void decode_kernel(
    const unsigned short* __restrict__ ef, const int* __restrict__ ipos,
    const int* __restrict__ recv, const int* __restrict__ send, int n_edges,
    const float* __restrict__ W1, const float* __restrict__ b1,
    const float* __restrict__ W2, const float* __restrict__ b2,
    float* __restrict__ out)
{
    int e = blockIdx.x * blockDim.x + threadIdx.x;
    if (e >= n_edges) return;
    int pos = ipos[e];
    const uint4* pe = (const uint4*)(ef + (size_t)pos * H);
    uint4 u0 = pe[0], u1 = pe[1];
    float x[H];
    unpack8(u0, x);
    unpack8(u1, x + 8);
    float h[H];
    #pragma unroll
    for (int o = 0; o < H; ++o) h[o] = b1[o];
    #pragma unroll
    for (int k = 0; k < H; ++k) {
        float xk = x[k];
        #pragma unroll
        for (int o = 0; o < H; ++o) h[o] += W1[o * H + k] * xk;
    }
    float val = b2[0];
    #pragma unroll
    for (int k = 0; k < H; ++k) {
        float hk = h[k] > 0.f ? h[k] : 0.f;
        val += W2[k] * hk;
    }
    int r = recv[e], s = send[e];
    val = (r >= s) ? val : 0.0f;
    out[e] = val;
    out[(size_t)n_edges + e] = bf2f(f2bf((float)r));
    out[2 * (size_t)n_edges + e] = bf2f(f2bf((float)s));
}

// ---------------- host launcher ----------------
extern "C" void kernel_launch(void* const* d_in, const int* in_sizes, int n_in,
                              void* d_out, int out_size, void* d_ws, size_t ws_size,
                              hipStream_t stream) {
    const unsigned short* nodes = (const unsigned short*)d_in[0];
    const unsigned short* edges = (const unsigned short*)d_in[1];
    const int* receivers = (const int*)d_in[2];
    const int* senders   = (const int*)d_in[3];
    const int* bi        = (const int*)d_in[4];
    const int n_nodes = in_sizes[0];
    const int n_edges = in_sizes[1];
    const int n_bi    = in_sizes[4] / 2;

    static const int wl[NW] = {16,16,256,16, 16,16,256,16,
                               3840,80,1280,80, 2560,80,1280,80,
                               256,16,16,1};
    WPtrs wp;
    {
        int off = 0;
        for (int a = 0; a < NW; ++a) {
            wp.src[a] = (const unsigned short*)d_in[5 + a];
            wp.len[a] = wl[a];
            wp.off[a] = off;
            off += wl[a];
        }
    }
    float* wf = (float*)d_ws;
    const float* Wf[NW];
    for (int a = 0; a < NW; ++a) Wf[a] = wf + wp.off[a];

    unsigned short* w1a = (unsigned short*)(wf + 10240);     // [5][2][64][8] bf16 A-frags
    unsigned short* w2a = w1a + 5 * 2 * 64 * 8;              // [5][64][8]
    unsigned short* nfb = w2a + 5 * 64 * 8;                  // [n_nodes][16] bf16
    unsigned short* efb = nfb + (size_t)n_nodes * H;         // [n_edges][16] bf16, PERMUTED
    int* cnt       = (int*)(efb + (size_t)n_edges * H);      // [n_nodes]
    int* row_start = cnt + n_nodes;                          // [n_nodes+1]
    int* cursor    = row_start + n_nodes + 1;                // [n_nodes]
    int* ipos      = cursor + n_nodes;                       // [n_edges]
    int* s_perm    = ipos + n_edges;                         // [n_edges]
    int* r_perm    = s_perm + n_edges;                       // [n_edges]
    int* blocksum  = r_perm + n_edges;                       // [<=1024]

    const int bn = 256;
    const int nb_scan = (n_nodes + SCAN_TILE - 1) / SCAN_TILE;
    const int nb_edge = (n_edges + bn - 1) / bn;
    const int nb_node = (n_nodes + bn - 1) / bn;

    cvt_weights_kernel<<<NW, 256, 0, stream>>>(wp, wf);
    mk_frags_kernel<<<1, 256, 0, stream>>>(
        (const unsigned short*)d_in[13], (const unsigned short*)d_in[15], w1a, w2a);
    encode_node_kernel<<<nb_node, bn, 0, stream>>>(
        nodes, n_nodes, Wf[0], Wf[1], Wf[2], Wf[3], nfb);

    // CSR build (once per launch; receivers are fixed input)
    hipMemsetAsync(cnt, 0, (size_t)n_nodes * 4, stream);
    hist_kernel<<<nb_edge, bn, 0, stream>>>(receivers, n_edges, cnt);
    scan_part_kernel<<<nb_scan, 256, 0, stream>>>(cnt, n_nodes, blocksum);
    scan_blocksums_kernel<<<1, 1024, 0, stream>>>(blocksum, nb_scan, n_nodes, row_start);
    scan_final_kernel<<<nb_scan, 256, 0, stream>>>(cnt, n_nodes, blocksum, row_start, cursor);
    expand_r_kernel<<<nb_node, bn, 0, stream>>>(row_start, n_nodes, r_perm);
    fill_encode_kernel<<<nb_edge, bn, 0, stream>>>(
        receivers, senders, edges, n_edges, cursor, ipos, s_perm, efb,
        Wf[4], Wf[5], Wf[6], Wf[7]);

    for (int r = 0; r < 5; ++r) {
        edge_update_mfma<<<nb_edge, bn, 0, stream>>>(
            nfb, efb, s_perm, r_perm, n_edges,
            w1a + r * 1024, w2a + r * 512,
            Wf[9] + r * H, Wf[11] + r * H);
        node_update_kernel<<<nb_node, bn, 0, stream>>>(
            nfb, efb, row_start, n_nodes,
            Wf[12] + r * 2 * H * H, Wf[13] + r * H,
            Wf[14] + r * H * H,     Wf[15] + r * H);
    }

    bi_avg_kernel<<<(n_bi + bn - 1) / bn, bn, 0, stream>>>(efb, ipos, bi, n_bi);
    decode_kernel<<<nb_edge, bn, 0, stream>>>(
        efb, ipos, receivers, senders, n_edges,
        Wf[16], Wf[17], Wf[18], Wf[19], (float*)d_out);
}